// Round 4
// baseline (365.207 us; speedup 1.0000x reference)
//
#include <hip/hip_runtime.h>
#include <stdint.h>
#include <stddef.h>

typedef unsigned short u16;
typedef __attribute__((ext_vector_type(8))) short s16x8;    // bf16 MFMA A/B frag (4 VGPR)
typedef __attribute__((ext_vector_type(8))) unsigned short u16x8;
typedef __attribute__((ext_vector_type(4))) unsigned short u16x4;
typedef __attribute__((ext_vector_type(4))) float f32x4;

typedef __attribute__((address_space(3))) void* as3_void_p;
typedef const __attribute__((address_space(1))) void* as1_cvoid_p;

#define GLD16(gp, lp) __builtin_amdgcn_global_load_lds((as1_cvoid_p)(gp), (as3_void_p)(lp), 16, 0, 0)

enum {
  NS = 2048, NF = 512, NH = 512, NW = 5,
  NROW = 32768,            // B*S
  K2 = NW * NF             // 2560
};

__device__ __forceinline__ u16 f2bf(float f) {
  unsigned u = __float_as_uint(f);
  u += 0x7FFFu + ((u >> 16) & 1u);     // round-to-nearest-even
  return (u16)(u >> 16);
}
__device__ __forceinline__ float bf2f(u16 v) {
  return __uint_as_float(((unsigned)v) << 16);
}

// ---------------- conversion kernels ----------------

__global__ __launch_bounds__(256) void cvtX(const float* __restrict__ X, u16* __restrict__ Xb) {
  int i = blockIdx.x * 256 + threadIdx.x;          // 0 .. NROW*NF/4
  f32x4 v = ((const f32x4*)X)[i];
  u16x4 o;
  o.x = f2bf(v.x); o.y = f2bf(v.y); o.z = f2bf(v.z); o.w = f2bf(v.w);
  ((u16x4*)Xb)[i] = o;
}

// Wt1[j][f]: j<512 -> Wq[:,j]; else Wk[:,j-512].  Wt2[h][k] = cnn_W[k][h], k = w*512+f.
__global__ __launch_bounds__(256) void cvtW(const float* __restrict__ Wq, const float* __restrict__ Wk,
                                            const float* __restrict__ cnnW,
                                            u16* __restrict__ Wt1, u16* __restrict__ Wt2) {
  int i = blockIdx.x * 256 + threadIdx.x;          // 0 .. 1024*512 + 512*2560
  if (i < 1024 * 512) {
    int j = i >> 9, f = i & 511;
    float v = (j < 512) ? Wq[(size_t)f * 512 + j] : Wk[(size_t)f * 512 + (j - 512)];
    Wt1[i] = f2bf(v);
  } else {
    int t = i - 1024 * 512;                        // < 512*2560
    int h = t / K2, k = t % K2;
    Wt2[t] = f2bf(cnnW[(size_t)k * 512 + h]);
  }
}

// ---------------- GEMM1: QKb[n][0:1024] = Xb @ Wt1^T  (bf16 out) ----------------
// 128x128 tile, BK=64, 4 waves (2x2), mfma 16x16x32 bf16, T2 XOR-swizzled LDS.
// LDS layout: tile (row, colbyte cb) lives at byte row*128 + (cb ^ ((row&7)<<4)).
// global_load_lds writes linearly -> pre-swizzle the SOURCE column (rule #21).

__global__ __launch_bounds__(256) void gemm_qk(const u16* __restrict__ Xb,
                                               const u16* __restrict__ Wt1,
                                               u16* __restrict__ QKb) {
  __shared__ u16 As[128 * 64];
  __shared__ u16 Bs[128 * 64];
  const int tid  = threadIdx.x;
  const int lane = tid & 63, wid = tid >> 6;
  const int wr = wid >> 1, wc = wid & 1;
  const int fr = lane & 15, fq = lane >> 4;
  // XCD-chunk swizzle: 2048 blocks, one XCD keeps contiguous row-panels
  const int wgid = (blockIdx.x & 7) * 256 + (blockIdx.x >> 3);
  const int brow = (wgid >> 3) * 128;
  const int bcol = (wgid & 7) * 128;

  f32x4 acc[4][4] = {};

  for (int kt = 0; kt < 8; ++kt) {
#pragma unroll
    for (int p = 0; p < 4; ++p) {
      int off = (p * 256 + tid) * 16;              // linear LDS byte offset
      int r = off >> 7;
      int cb = (off & 127) ^ ((r & 7) << 4);       // inverse-swizzled source column byte
      const u16* ga = Xb  + (size_t)(brow + r) * NF + kt * 64 + (cb >> 1);
      const u16* gb = Wt1 + (size_t)(bcol + r) * NF + kt * 64 + (cb >> 1);
      GLD16(ga, (char*)As + off);
      GLD16(gb, (char*)Bs + off);
    }
    __syncthreads();
#pragma unroll
    for (int kk = 0; kk < 2; ++kk) {
      s16x8 af[4], bfr[4];
#pragma unroll
      for (int m = 0; m < 4; ++m) {
        int row = wr * 64 + m * 16 + fr;
        af[m] = *(const s16x8*)((const char*)As + row * 128 + ((kk * 64 + fq * 16) ^ ((row & 7) << 4)));
      }
#pragma unroll
      for (int n = 0; n < 4; ++n) {
        int row = wc * 64 + n * 16 + fr;
        bfr[n] = *(const s16x8*)((const char*)Bs + row * 128 + ((kk * 64 + fq * 16) ^ ((row & 7) << 4)));
      }
#pragma unroll
      for (int m = 0; m < 4; ++m)
#pragma unroll
        for (int n = 0; n < 4; ++n)
          acc[m][n] = __builtin_amdgcn_mfma_f32_16x16x32_bf16(af[m], bfr[n], acc[m][n], 0, 0, 0);
    }
    __syncthreads();
  }

#pragma unroll
  for (int m = 0; m < 4; ++m)
#pragma unroll
    for (int n = 0; n < 4; ++n)
#pragma unroll
      for (int r = 0; r < 4; ++r) {
        int row = brow + wr * 64 + m * 16 + fq * 4 + r;
        int col = bcol + wc * 64 + n * 16 + fr;
        QKb[(size_t)row * 1024 + col] = f2bf(acc[m][n][r]);
      }
}

// ---------------- scores + softmax -> att[n][5] ----------------
// one wave per row n; lane covers h = lane*8 .. lane*8+7 (vectorized u16x8 loads)

__global__ __launch_bounds__(256) void scores_att(const u16* __restrict__ QKb,
                                                  const float* __restrict__ vatt,
                                                  float* __restrict__ att) {
  const int lane = threadIdx.x & 63;
  const int wid  = threadIdx.x >> 6;
  const int n = blockIdx.x * 4 + wid;
  const int s = n & (NS - 1);
  const int h0 = lane * 8;

  u16x8 qv = *(const u16x8*)(QKb + (size_t)n * 1024 + h0);
  f32x4 va0 = *(const f32x4*)(vatt + h0);
  f32x4 va1 = *(const f32x4*)(vatt + h0 + 4);
  float q[8], vv[8];
#pragma unroll
  for (int j = 0; j < 8; ++j) q[j] = bf2f(qv[j]);
  vv[0] = va0.x; vv[1] = va0.y; vv[2] = va0.z; vv[3] = va0.w;
  vv[4] = va1.x; vv[5] = va1.y; vv[6] = va1.z; vv[7] = va1.w;

  float sc[5];
#pragma unroll
  for (int w = 0; w < 5; ++w) {
    int sp = s + w - 2;
    u16x8 kv = {0, 0, 0, 0, 0, 0, 0, 0};
    if (sp >= 0 && sp < NS)
      kv = *(const u16x8*)(QKb + (size_t)(n + w - 2) * 1024 + 512 + h0);
    float acc = 0.f;
#pragma unroll
    for (int j = 0; j < 8; ++j) {
      float x = q[j] + bf2f(kv[j]);
      x = fminf(fmaxf(x, -15.f), 15.f);
      float e = __expf(2.f * x);
      acc += vv[j] * ((e - 1.f) / (e + 1.f));     // tanh(x)
    }
    sc[w] = acc;
  }
#pragma unroll
  for (int w = 0; w < 5; ++w)
#pragma unroll
    for (int o = 32; o > 0; o >>= 1)
      sc[w] += __shfl_xor(sc[w], o, 64);

  if (lane == 0) {
    float m = sc[0];
#pragma unroll
    for (int w = 1; w < 5; ++w) m = fmaxf(m, sc[w]);
    float e[5], sum = 0.f;
#pragma unroll
    for (int w = 0; w < 5; ++w) { e[w] = __expf(sc[w] - m); sum += e[w]; }
    float inv = 1.f / sum;
#pragma unroll
    for (int w = 0; w < 5; ++w) att[(size_t)n * 5 + w] = e[w] * inv;
  }
}

// ---------------- GEMM2 (fold epilogue): out[n][h] = b[h] + sum_w att[n][w]*(X[n+w-2]@W_w)[h] ----
// 128x64 block tile, 4 waves (2x2), wave tile 64x32 -> acc+accOut = 64 VGPR (occupancy fix).
// Per w: A-tile = UNSCALED shifted rows of Xb (pure global_load_lds). After each w's
// K-range, fold acc into accOut with att[n][w] (masked 0 at seq OOB). Rows clamped in-bounds.

__global__ __launch_bounds__(256, 4) void gemm_out(const u16* __restrict__ Xb,
                                                   const u16* __restrict__ Wt2,
                                                   const float* __restrict__ att,
                                                   const float* __restrict__ cnnb,
                                                   float* __restrict__ out) {
  __shared__ u16 As[128 * 64];                     // 16 KB
  __shared__ u16 Bs[64 * 64];                      //  8 KB
  __shared__ float att_s[128 * 5];
  const int tid  = threadIdx.x;
  const int lane = tid & 63, wid = tid >> 6;
  const int wr = wid >> 1, wc = wid & 1;
  const int fr = lane & 15, fq = lane >> 4;
  // XCD-chunk swizzle: 2048 blocks, contiguous row-panels per XCD (col-fast within)
  const int wgid = (blockIdx.x & 7) * 256 + (blockIdx.x >> 3);
  const int brow = (wgid >> 3) * 128;
  const int bcol = (wgid & 7) * 64;

  if (tid < 128) {
    int s = (brow + tid) & (NS - 1);
#pragma unroll
    for (int w = 0; w < 5; ++w) {
      int sp = s + w - 2;
      att_s[tid * 5 + w] = (sp >= 0 && sp < NS) ? att[(size_t)(brow + tid) * 5 + w] : 0.f;
    }
  }

  f32x4 acc[4][2] = {};
  f32x4 accOut[4][2] = {};

  for (int w = 0; w < 5; ++w) {
    for (int kt = 0; kt < 8; ++kt) {
#pragma unroll
      for (int p = 0; p < 6; ++p) {
        int off = (p * 256 + tid) * 16;            // 0 .. 24 KB
        if (off < 16384) {                         // A: 128 rows x 64 k
          int r = off >> 7;
          int cb = (off & 127) ^ ((r & 7) << 4);
          int g = brow + r + w - 2;
          g = g < 0 ? 0 : (g >= NROW ? NROW - 1 : g);   // clamp; fold weight 0 for invalid
          GLD16(Xb + (size_t)g * NF + kt * 64 + (cb >> 1), (char*)As + off);
        } else {                                   // B: 64 rows x 64 k
          int ob = off - 16384;
          int r = ob >> 7;
          int cb = (ob & 127) ^ ((r & 7) << 4);
          GLD16(Wt2 + (size_t)(bcol + r) * K2 + w * 512 + kt * 64 + (cb >> 1), (char*)Bs + ob);
        }
      }
      __syncthreads();
#pragma unroll
      for (int kk = 0; kk < 2; ++kk) {
        s16x8 af[4], bfr[2];
#pragma unroll
        for (int m = 0; m < 4; ++m) {
          int row = wr * 64 + m * 16 + fr;
          af[m] = *(const s16x8*)((const char*)As + row * 128 + ((kk * 64 + fq * 16) ^ ((row & 7) << 4)));
        }
#pragma unroll
        for (int n = 0; n < 2; ++n) {
          int row = wc * 32 + n * 16 + fr;
          bfr[n] = *(const s16x8*)((const char*)Bs + row * 128 + ((kk * 64 + fq * 16) ^ ((row & 7) << 4)));
        }
#pragma unroll
        for (int m = 0; m < 4; ++m)
#pragma unroll
          for (int n = 0; n < 2; ++n)
            acc[m][n] = __builtin_amdgcn_mfma_f32_16x16x32_bf16(af[m], bfr[n], acc[m][n], 0, 0, 0);
      }
      __syncthreads();
    }
    // fold: accOut += att[row][w] * acc; acc = 0
#pragma unroll
    for (int m = 0; m < 4; ++m) {
      float a0 = att_s[(wr * 64 + m * 16 + fq * 4 + 0) * 5 + w];
      float a1 = att_s[(wr * 64 + m * 16 + fq * 4 + 1) * 5 + w];
      float a2 = att_s[(wr * 64 + m * 16 + fq * 4 + 2) * 5 + w];
      float a3 = att_s[(wr * 64 + m * 16 + fq * 4 + 3) * 5 + w];
#pragma unroll
      for (int n = 0; n < 2; ++n) {
        accOut[m][n][0] += a0 * acc[m][n][0];
        accOut[m][n][1] += a1 * acc[m][n][1];
        accOut[m][n][2] += a2 * acc[m][n][2];
        accOut[m][n][3] += a3 * acc[m][n][3];
        acc[m][n] = f32x4{0.f, 0.f, 0.f, 0.f};
      }
    }
  }

#pragma unroll
  for (int m = 0; m < 4; ++m)
#pragma unroll
    for (int n = 0; n < 2; ++n)
#pragma unroll
      for (int r = 0; r < 4; ++r) {
        int row = brow + wr * 64 + m * 16 + fq * 4 + r;
        int col = bcol + wc * 32 + n * 16 + fr;
        out[(size_t)row * NH + col] = accOut[m][n][r] + cnnb[col];
      }
}

// ---------------- launch ----------------

extern "C" void kernel_launch(void* const* d_in, const int* in_sizes, int n_in,
                              void* d_out, int out_size, void* d_ws, size_t ws_size,
                              hipStream_t stream) {
  const float* X    = (const float*)d_in[0];
  const float* Wq   = (const float*)d_in[1];
  const float* Wk   = (const float*)d_in[2];
  const float* vatt = (const float*)d_in[3];
  const float* cnnW = (const float*)d_in[4];
  const float* cnnb = (const float*)d_in[5];
  float* out = (float*)d_out;

  char* ws = (char*)d_ws;
  u16*   Xb  = (u16*)ws;                            // 32768*512*2  =  33,554,432 B
  u16*   Wt1 = (u16*)(ws + 33554432);               // 1024*512*2   =   1,048,576 B
  u16*   Wt2 = (u16*)(ws + 34603008);               // 512*2560*2   =   2,621,440 B
  u16*   QKb = (u16*)(ws + 37224448);               // 32768*1024*2 =  67,108,864 B
  float* att = (float*)(ws + 104333312);            // 32768*5*4    =     655,360 B
                                                    // total ~105 MB

  cvtX<<<dim3(NROW * NF / 4 / 256), dim3(256), 0, stream>>>(X, Xb);
  cvtW<<<dim3((1024 * 512 + 512 * K2) / 256), dim3(256), 0, stream>>>(Wq, Wk, cnnW, Wt1, Wt2);
  gemm_qk<<<dim3(2048), dim3(256), 0, stream>>>(Xb, Wt1, QKb);
  scores_att<<<dim3(NROW / 4), dim3(256), 0, stream>>>(QKb, vatt, att);
  gemm_out<<<dim3(2048), dim3(256), 0, stream>>>(Xb, Wt2, att, cnnb, out);
}

// Round 5
// 208.741 us; speedup vs baseline: 1.7496x; 1.7496x over previous
//
#include <hip/hip_runtime.h>
#include <stdint.h>
#include <stddef.h>

typedef unsigned short u16;
typedef __attribute__((ext_vector_type(8))) short s16x8;    // bf16 MFMA A/B frag (4 VGPR)
typedef __attribute__((ext_vector_type(8))) unsigned short u16x8;
typedef __attribute__((ext_vector_type(4))) unsigned short u16x4;
typedef __attribute__((ext_vector_type(4))) float f32x4;

typedef __attribute__((address_space(3))) void* as3_void_p;
typedef const __attribute__((address_space(1))) void* as1_cvoid_p;

#define GLD16(gp, lp) __builtin_amdgcn_global_load_lds((as1_cvoid_p)(gp), (as3_void_p)(lp), 16, 0, 0)

enum {
  NS = 2048, NF = 512, NH = 512, NW = 5,
  NROW = 32768,            // B*S
  K2 = NW * NF             // 2560
};

__device__ __forceinline__ u16 f2bf(float f) {
  unsigned u = __float_as_uint(f);
  u += 0x7FFFu + ((u >> 16) & 1u);     // round-to-nearest-even
  return (u16)(u >> 16);
}
__device__ __forceinline__ float bf2f(u16 v) {
  return __uint_as_float(((unsigned)v) << 16);
}

// ---------------- conversion kernels ----------------

__global__ __launch_bounds__(256) void cvtX(const float* __restrict__ X, u16* __restrict__ Xb) {
  int i = blockIdx.x * 256 + threadIdx.x;          // 0 .. NROW*NF/4
  f32x4 v = ((const f32x4*)X)[i];
  u16x4 o;
  o.x = f2bf(v.x); o.y = f2bf(v.y); o.z = f2bf(v.z); o.w = f2bf(v.w);
  ((u16x4*)Xb)[i] = o;
}

// Wt1[j][f]: j<512 -> Wq[:,j]; else Wk[:,j-512].  Wt2[h][k] = cnn_W[k][h], k = w*512+f.
__global__ __launch_bounds__(256) void cvtW(const float* __restrict__ Wq, const float* __restrict__ Wk,
                                            const float* __restrict__ cnnW,
                                            u16* __restrict__ Wt1, u16* __restrict__ Wt2) {
  int i = blockIdx.x * 256 + threadIdx.x;          // 0 .. 1024*512 + 512*2560
  if (i < 1024 * 512) {
    int j = i >> 9, f = i & 511;
    float v = (j < 512) ? Wq[(size_t)f * 512 + j] : Wk[(size_t)f * 512 + (j - 512)];
    Wt1[i] = f2bf(v);
  } else {
    int t = i - 1024 * 512;                        // < 512*2560
    int h = t / K2, k = t % K2;
    Wt2[t] = f2bf(cnnW[(size_t)k * 512 + h]);
  }
}

// ---------------- GEMM1: QKb[n][0:1024] = Xb @ Wt1^T  (bf16 out) ----------------
// 128x128 tile, BK=64, 4 waves (2x2), mfma 16x16x32 bf16, T2 XOR-swizzled LDS.

__global__ __launch_bounds__(256) void gemm_qk(const u16* __restrict__ Xb,
                                               const u16* __restrict__ Wt1,
                                               u16* __restrict__ QKb) {
  __shared__ u16 As[128 * 64];
  __shared__ u16 Bs[128 * 64];
  const int tid  = threadIdx.x;
  const int lane = tid & 63, wid = tid >> 6;
  const int wr = wid >> 1, wc = wid & 1;
  const int fr = lane & 15, fq = lane >> 4;
  // XCD-chunk swizzle: 2048 blocks, one XCD keeps contiguous row-panels
  const int wgid = (blockIdx.x & 7) * 256 + (blockIdx.x >> 3);
  const int brow = (wgid >> 3) * 128;
  const int bcol = (wgid & 7) * 128;

  f32x4 acc[4][4] = {};

  for (int kt = 0; kt < 8; ++kt) {
#pragma unroll
    for (int p = 0; p < 4; ++p) {
      int off = (p * 256 + tid) * 16;              // linear LDS byte offset
      int r = off >> 7;
      int cb = (off & 127) ^ ((r & 7) << 4);       // inverse-swizzled source column byte
      const u16* ga = Xb  + (size_t)(brow + r) * NF + kt * 64 + (cb >> 1);
      const u16* gb = Wt1 + (size_t)(bcol + r) * NF + kt * 64 + (cb >> 1);
      GLD16(ga, (char*)As + off);
      GLD16(gb, (char*)Bs + off);
    }
    __syncthreads();
#pragma unroll
    for (int kk = 0; kk < 2; ++kk) {
      s16x8 af[4], bfr[4];
#pragma unroll
      for (int m = 0; m < 4; ++m) {
        int row = wr * 64 + m * 16 + fr;
        af[m] = *(const s16x8*)((const char*)As + row * 128 + ((kk * 64 + fq * 16) ^ ((row & 7) << 4)));
      }
#pragma unroll
      for (int n = 0; n < 4; ++n) {
        int row = wc * 64 + n * 16 + fr;
        bfr[n] = *(const s16x8*)((const char*)Bs + row * 128 + ((kk * 64 + fq * 16) ^ ((row & 7) << 4)));
      }
#pragma unroll
      for (int m = 0; m < 4; ++m)
#pragma unroll
        for (int n = 0; n < 4; ++n)
          acc[m][n] = __builtin_amdgcn_mfma_f32_16x16x32_bf16(af[m], bfr[n], acc[m][n], 0, 0, 0);
    }
    __syncthreads();
  }

#pragma unroll
  for (int m = 0; m < 4; ++m)
#pragma unroll
    for (int n = 0; n < 4; ++n)
#pragma unroll
      for (int r = 0; r < 4; ++r) {
        int row = brow + wr * 64 + m * 16 + fq * 4 + r;
        int col = bcol + wc * 64 + n * 16 + fr;
        QKb[(size_t)row * 1024 + col] = f2bf(acc[m][n][r]);
      }
}

// ---------------- scores + softmax -> att[n][5] ----------------

__global__ __launch_bounds__(256) void scores_att(const u16* __restrict__ QKb,
                                                  const float* __restrict__ vatt,
                                                  float* __restrict__ att) {
  const int lane = threadIdx.x & 63;
  const int wid  = threadIdx.x >> 6;
  const int n = blockIdx.x * 4 + wid;
  const int s = n & (NS - 1);
  const int h0 = lane * 8;

  u16x8 qv = *(const u16x8*)(QKb + (size_t)n * 1024 + h0);
  f32x4 va0 = *(const f32x4*)(vatt + h0);
  f32x4 va1 = *(const f32x4*)(vatt + h0 + 4);
  float q[8], vv[8];
#pragma unroll
  for (int j = 0; j < 8; ++j) q[j] = bf2f(qv[j]);
  vv[0] = va0.x; vv[1] = va0.y; vv[2] = va0.z; vv[3] = va0.w;
  vv[4] = va1.x; vv[5] = va1.y; vv[6] = va1.z; vv[7] = va1.w;

  float sc[5];
#pragma unroll
  for (int w = 0; w < 5; ++w) {
    int sp = s + w - 2;
    u16x8 kv = {0, 0, 0, 0, 0, 0, 0, 0};
    if (sp >= 0 && sp < NS)
      kv = *(const u16x8*)(QKb + (size_t)(n + w - 2) * 1024 + 512 + h0);
    float acc = 0.f;
#pragma unroll
    for (int j = 0; j < 8; ++j) {
      float x = q[j] + bf2f(kv[j]);
      x = fminf(fmaxf(x, -15.f), 15.f);
      float e = __expf(2.f * x);
      acc += vv[j] * ((e - 1.f) / (e + 1.f));     // tanh(x)
    }
    sc[w] = acc;
  }
#pragma unroll
  for (int w = 0; w < 5; ++w)
#pragma unroll
    for (int o = 32; o > 0; o >>= 1)
      sc[w] += __shfl_xor(sc[w], o, 64);

  if (lane == 0) {
    float m = sc[0];
#pragma unroll
    for (int w = 1; w < 5; ++w) m = fmaxf(m, sc[w]);
    float e[5], sum = 0.f;
#pragma unroll
    for (int w = 0; w < 5; ++w) { e[w] = __expf(sc[w] - m); sum += e[w]; }
    float inv = 1.f / sum;
#pragma unroll
    for (int w = 0; w < 5; ++w) att[(size_t)n * 5 + w] = e[w] * inv;
  }
}

// ---------------- GEMM2 (fold epilogue): out[n][h] = b[h] + sum_w att[n][w]*(X[n+w-2]@W_w)[h] ----
// 128x128 block tile (round-3 locality: FETCH ~58MB), 8 waves (2x4), wave tile 64x32
// -> acc+accOut = 64 VGPR; __launch_bounds__(512,4) -> 2 blocks/CU, 50% occupancy.
// Per w: A = unscaled shifted Xb rows (pure global_load_lds); fold per-w with att (OOB rows weight 0).

__global__ __launch_bounds__(512, 4) void gemm_out(const u16* __restrict__ Xb,
                                                   const u16* __restrict__ Wt2,
                                                   const float* __restrict__ att,
                                                   const float* __restrict__ cnnb,
                                                   float* __restrict__ out) {
  __shared__ u16 As[128 * 64];                     // 16 KB
  __shared__ u16 Bs[128 * 64];                     // 16 KB
  __shared__ float att_s[128 * 5];
  const int tid  = threadIdx.x;
  const int lane = tid & 63, wid = tid >> 6;
  const int wr = wid >> 2, wc = wid & 3;           // 2 x 4 wave grid, wave tile 64x32
  const int fr = lane & 15, fq = lane >> 4;
  // XCD-chunk swizzle: 1024 blocks, contiguous row-panels per XCD (col-fast within)
  const int wgid = (blockIdx.x & 7) * 128 + (blockIdx.x >> 3);
  const int brow = (wgid >> 2) * 128;
  const int bcol = (wgid & 3) * 128;

  if (tid < 128) {
    int s = (brow + tid) & (NS - 1);
#pragma unroll
    for (int w = 0; w < 5; ++w) {
      int sp = s + w - 2;
      att_s[tid * 5 + w] = (sp >= 0 && sp < NS) ? att[(size_t)(brow + tid) * 5 + w] : 0.f;
    }
  }

  // tid-static staging geometry: thread covers LDS byte off(p) = (p*512+tid)*16,
  // p=0,1 -> As rows r=p*64+(tid>>3); p=2,3 -> Bs rows r=(p-2)*64+(tid>>3).
  const int rsub = tid >> 3;                                   // 0..63
  const int cb   = (((tid & 7) ^ (rsub & 7)) << 4);            // swizzled source column byte
  const int ldsA0 = tid * 16;                                  // p=0
  const int ldsA1 = 8192 + tid * 16;                           // p=1
  const int ldsB0 = tid * 16;                                  // p=2 (Bs)
  const int ldsB1 = 8192 + tid * 16;                           // p=3 (Bs)
  // B global row bases (h rows), invariant over w/kt except +w*1024B, +kt*128B
  const char* gB0 = (const char*)(Wt2 + (size_t)(bcol + rsub) * K2) + cb;
  const char* gB1 = (const char*)(Wt2 + (size_t)(bcol + 64 + rsub) * K2) + cb;

  f32x4 acc[4][2] = {};
  f32x4 accOut[4][2] = {};

  for (int w = 0; w < 5; ++w) {
    // per-w A row bases (clamped; invalid rows get fold weight 0)
    int g0 = brow + rsub + w - 2;
    int g1 = brow + 64 + rsub + w - 2;
    g0 = g0 < 0 ? 0 : (g0 >= NROW ? NROW - 1 : g0);
    g1 = g1 < 0 ? 0 : (g1 >= NROW ? NROW - 1 : g1);
    const char* gA0 = (const char*)(Xb + (size_t)g0 * NF) + cb;
    const char* gA1 = (const char*)(Xb + (size_t)g1 * NF) + cb;
    const char* gBw0 = gB0 + w * 1024;
    const char* gBw1 = gB1 + w * 1024;

    for (int kt = 0; kt < 8; ++kt) {
      GLD16(gA0  + kt * 128, (char*)As + ldsA0);
      GLD16(gA1  + kt * 128, (char*)As + ldsA1);
      GLD16(gBw0 + kt * 128, (char*)Bs + ldsB0);
      GLD16(gBw1 + kt * 128, (char*)Bs + ldsB1);
      __syncthreads();
#pragma unroll
      for (int kk = 0; kk < 2; ++kk) {
        s16x8 af[4], bfr[2];
#pragma unroll
        for (int m = 0; m < 4; ++m) {
          int row = wr * 64 + m * 16 + fr;
          af[m] = *(const s16x8*)((const char*)As + row * 128 + ((kk * 64 + fq * 16) ^ ((row & 7) << 4)));
        }
#pragma unroll
        for (int n = 0; n < 2; ++n) {
          int row = wc * 32 + n * 16 + fr;
          bfr[n] = *(const s16x8*)((const char*)Bs + row * 128 + ((kk * 64 + fq * 16) ^ ((row & 7) << 4)));
        }
#pragma unroll
        for (int m = 0; m < 4; ++m)
#pragma unroll
          for (int n = 0; n < 2; ++n)
            acc[m][n] = __builtin_amdgcn_mfma_f32_16x16x32_bf16(af[m], bfr[n], acc[m][n], 0, 0, 0);
      }
      __syncthreads();
    }
    // fold: accOut += att[row][w] * acc; acc = 0  (registers + att_s only, no As/Bs hazard)
#pragma unroll
    for (int m = 0; m < 4; ++m) {
      float a0 = att_s[(wr * 64 + m * 16 + fq * 4 + 0) * 5 + w];
      float a1 = att_s[(wr * 64 + m * 16 + fq * 4 + 1) * 5 + w];
      float a2 = att_s[(wr * 64 + m * 16 + fq * 4 + 2) * 5 + w];
      float a3 = att_s[(wr * 64 + m * 16 + fq * 4 + 3) * 5 + w];
#pragma unroll
      for (int n = 0; n < 2; ++n) {
        accOut[m][n][0] += a0 * acc[m][n][0];
        accOut[m][n][1] += a1 * acc[m][n][1];
        accOut[m][n][2] += a2 * acc[m][n][2];
        accOut[m][n][3] += a3 * acc[m][n][3];
        acc[m][n] = f32x4{0.f, 0.f, 0.f, 0.f};
      }
    }
  }

#pragma unroll
  for (int m = 0; m < 4; ++m)
#pragma unroll
    for (int n = 0; n < 2; ++n)
#pragma unroll
      for (int r = 0; r < 4; ++r) {
        int row = brow + wr * 64 + m * 16 + fq * 4 + r;
        int col = bcol + wc * 32 + n * 16 + fr;
        out[(size_t)row * NH + col] = accOut[m][n][r] + cnnb[col];
      }
}

// ---------------- launch ----------------

extern "C" void kernel_launch(void* const* d_in, const int* in_sizes, int n_in,
                              void* d_out, int out_size, void* d_ws, size_t ws_size,
                              hipStream_t stream) {
  const float* X    = (const float*)d_in[0];
  const float* Wq   = (const float*)d_in[1];
  const float* Wk   = (const float*)d_in[2];
  const float* vatt = (const float*)d_in[3];
  const float* cnnW = (const float*)d_in[4];
  const float* cnnb = (const float*)d_in[5];
  float* out = (float*)d_out;

  char* ws = (char*)d_ws;
  u16*   Xb  = (u16*)ws;                            // 32768*512*2  =  33,554,432 B
  u16*   Wt1 = (u16*)(ws + 33554432);               // 1024*512*2   =   1,048,576 B
  u16*   Wt2 = (u16*)(ws + 34603008);               // 512*2560*2   =   2,621,440 B
  u16*   QKb = (u16*)(ws + 37224448);               // 32768*1024*2 =  67,108,864 B
  float* att = (float*)(ws + 104333312);            // 32768*5*4    =     655,360 B
                                                    // total ~105 MB

  cvtX<<<dim3(NROW * NF / 4 / 256), dim3(256), 0, stream>>>(X, Xb);
  cvtW<<<dim3((1024 * 512 + 512 * K2) / 256), dim3(256), 0, stream>>>(Wq, Wk, cnnW, Wt1, Wt2);
  gemm_qk<<<dim3(2048), dim3(256), 0, stream>>>(Xb, Wt1, QKb);
  scores_att<<<dim3(NROW / 4), dim3(256), 0, stream>>>(QKb, vatt, att);
  gemm_out<<<dim3(1024), dim3(512), 0, stream>>>(Xb, Wt2, att, cnnb, out);
}